// Round 1
// 239.471 us; speedup vs baseline: 1.0075x; 1.0075x over previous
//
#include <hip/hip_runtime.h>
#include <hip/hip_bf16.h>

// EAConv: EM-routing neighbor aggregation + temporal blend.
// T=3, b=1, n=50000, d=64, m=16, K=4, dd=16.
// R8 = R7 structure, with two latency-targeted changes:
//  - __launch_bounds__(256, 4): VGPR budget 128 (was effectively 64 at
//    8 waves/SIMD). At 36 VGPRs the compiler was REMATERIALIZING the z/xk
//    gathers inside iters 1-2 (48+ floats of live state cannot fit in 36
//    regs without re-loading), putting scattered L1/L2 gathers on the
//    iteration dependency chain 3x per wave. Keep everything resident.
//  - 4-way partial accumulators for all length-16 reduction chains
//    (sx/sz/dot/ns/na): serial 16-FMA chain (~64 cy latency) -> ~24 cy.
// Lane = (k,m): m=lane&15 neighbor, k=lane>>4 factor; lane holds neighbor
// m's full 16-dim factor-k row.

constexpr int T  = 3;
constexpr int N  = 50000;
constexpr int D  = 64;
constexpr int M  = 16;
constexpr int DD = 16;
constexpr float EPS2 = 1e-24f;  // (1e-12)^2

template <int CTRL>
__device__ __forceinline__ float dpp_add(float v) {
    // mov_dpp has an implicit UNDEF old operand -> eligible for fusion into
    // v_add_f32_dpp. row_ror within a 16-lane row: every lane valid.
    int rot = __builtin_amdgcn_mov_dpp(__float_as_int(v), CTRL, 0xF, 0xF, false);
    return v + __int_as_float(rot);
}
// sum over the 16 lanes of a row; result broadcast to every lane of the row
__device__ __forceinline__ float rowsum16(float v) {
    v = dpp_add<0x128>(v);  // row_ror:8
    v = dpp_add<0x124>(v);  // row_ror:4
    v = dpp_add<0x122>(v);  // row_ror:2
    v = dpp_add<0x121>(v);  // row_ror:1
    return v;
}

__global__ __launch_bounds__(256, 4) void eaconv_agg(
    const float* __restrict__ x_all,   // [T,N,D]
    const int*   __restrict__ nbr_all, // [T,N,M]
    float*       __restrict__ out)     // [T,N,D] <- U_t (pre-blend)
{
    const int wave = (blockIdx.x * blockDim.x + threadIdx.x) >> 6;
    const int lane = threadIdx.x & 63;
    if (wave >= T * N) return;
    const int t = wave / N;
    const int i = wave - t * N;
    const int m = lane & 15;
    const int k = lane >> 4;

    const float* x = x_all + (size_t)t * N * D;

    int j = nbr_all[((size_t)t * N + i) * M + m];
    const bool valid = (unsigned)j < (unsigned)N;
    j = valid ? j : 0;

    // own factor row (broadcast addr across row) + neighbor row (scattered)
    const float4* xr = (const float4*)(x + (size_t)i * D + k * DD);
    const float4* zr = (const float4*)(x + (size_t)j * D + k * DD);
    float4 a0 = xr[0], a1 = xr[1], a2 = xr[2], a3 = xr[3];
    float4 b0 = zr[0], b1 = zr[1], b2 = zr[2], b3 = zr[3];
    float xk[DD] = {a0.x,a0.y,a0.z,a0.w, a1.x,a1.y,a1.z,a1.w,
                    a2.x,a2.y,a2.z,a2.w, a3.x,a3.y,a3.z,a3.w};
    float z[DD]  = {b0.x,b0.y,b0.z,b0.w, b1.x,b1.y,b1.z,b1.w,
                    b2.x,b2.y,b2.z,b2.w, b3.x,b3.y,b3.z,b3.w};

    // xk: normalize in place.  z: stays RAW; rz folds into the weights.
    // 4-way partial sums: cut the dependent-FMA chain latency 64cy -> ~24cy.
    float sxp0 = xk[0]*xk[0], sxp1 = xk[1]*xk[1],
          sxp2 = xk[2]*xk[2], sxp3 = xk[3]*xk[3];
    float szp0 = z[0]*z[0],   szp1 = z[1]*z[1],
          szp2 = z[2]*z[2],   szp3 = z[3]*z[3];
#pragma unroll
    for (int p = 4; p < DD; p += 4) {
        sxp0 = fmaf(xk[p+0], xk[p+0], sxp0);
        sxp1 = fmaf(xk[p+1], xk[p+1], sxp1);
        sxp2 = fmaf(xk[p+2], xk[p+2], sxp2);
        sxp3 = fmaf(xk[p+3], xk[p+3], sxp3);
        szp0 = fmaf(z[p+0],  z[p+0],  szp0);
        szp1 = fmaf(z[p+1],  z[p+1],  szp1);
        szp2 = fmaf(z[p+2],  z[p+2],  szp2);
        szp3 = fmaf(z[p+3],  z[p+3],  szp3);
    }
    const float sx = (sxp0 + sxp1) + (sxp2 + sxp3);
    const float sz = (szp0 + szp1) + (szp2 + szp3);
    const float rx = __builtin_amdgcn_rsqf(fmaxf(sx, EPS2));
    float rz = __builtin_amdgcn_rsqf(fmaxf(sz, EPS2));
    if (!valid) rz = 0.f;
#pragma unroll
    for (int p = 0; p < DD; ++p) xk[p] *= rx;

    // ---- iter 0: u = sum_m rz_m*z_m + 4*xk (direction; scale via logit) ----
    float u[DD];
#pragma unroll
    for (int p = 0; p < DD; ++p)
        u[p] = fmaf(xk[p], 4.0f, rowsum16(z[p] * rz));
    float np0 = u[0]*u[0], np1 = u[1]*u[1], np2 = u[2]*u[2], np3 = u[3]*u[3];
#pragma unroll
    for (int p = 4; p < DD; p += 4) {
        np0 = fmaf(u[p+0], u[p+0], np0);
        np1 = fmaf(u[p+1], u[p+1], np1);
        np2 = fmaf(u[p+2], u[p+2], np2);
        np3 = fmaf(u[p+3], u[p+3], np3);
    }
    float inv = __builtin_amdgcn_rsqf(fmaxf((np0+np1)+(np2+np3), EPS2));

    // ---- iters 1..2 ----
#pragma unroll
    for (int it = 1; it < 3; ++it) {
        float dp0 = z[0]*u[0], dp1 = z[1]*u[1],
              dp2 = z[2]*u[2], dp3 = z[3]*u[3];
#pragma unroll
        for (int p = 4; p < DD; p += 4) {
            dp0 = fmaf(z[p+0], u[p+0], dp0);
            dp1 = fmaf(z[p+1], u[p+1], dp1);
            dp2 = fmaf(z[p+2], u[p+2], dp2);
            dp3 = fmaf(z[p+3], u[p+3], dp3);
        }
        const float dot = (dp0 + dp1) + (dp2 + dp3);
        const float logit = dot * (rz * inv);  // = zhat . uhat, in [-1,1]
        const float e = __expf(logit);         // no max-sub needed (bounded)
        float es = e + __shfl_xor(e, 16, 64);  // softmax denom over 4 factors
        es += __shfl_xor(es, 32, 64);
        const float wf = e * __builtin_amdgcn_rcpf(es) * rz;  // weight*rz
#pragma unroll
        for (int p = 0; p < DD; ++p)
            u[p] = xk[p] + rowsum16(z[p] * wf);
        if (it < 2) {  // no normalize after the last iteration
            float a0n = u[0]*u[0], a1n = u[1]*u[1],
                  a2n = u[2]*u[2], a3n = u[3]*u[3];
#pragma unroll
            for (int p = 4; p < DD; p += 4) {
                a0n = fmaf(u[p+0], u[p+0], a0n);
                a1n = fmaf(u[p+1], u[p+1], a1n);
                a2n = fmaf(u[p+2], u[p+2], a2n);
                a3n = fmaf(u[p+3], u[p+3], a3n);
            }
            inv = __builtin_amdgcn_rsqf(fmaxf((a0n+a1n)+(a2n+a3n), EPS2));
        }
    }

    // store (clean 37.5 MB pattern): lanes m=0..3 write one float4 each
    float* o = out + ((size_t)t * N + i) * D + k * DD;
    if (m == 0) ((float4*)o)[0] = make_float4(u[0],  u[1],  u[2],  u[3]);
    if (m == 1) ((float4*)o)[1] = make_float4(u[4],  u[5],  u[6],  u[7]);
    if (m == 2) ((float4*)o)[2] = make_float4(u[8],  u[9],  u[10], u[11]);
    if (m == 3) ((float4*)o)[3] = make_float4(u[12], u[13], u[14], u[15]);
}

// Temporal blend, closed form (sigmoid(0)=0.5, sigmoid(1)=0.7310585786):
//   e0 = u0;  e1 = 0.25*u0 + 0.5*u1;  e2 = (0.5*u0 + s1*e1)*0.25 + 0.5*u2
__global__ __launch_bounds__(256) void eaconv_combine(float* __restrict__ out) {
    const int nd4 = N * D / 4;
    int idx = blockIdx.x * blockDim.x + threadIdx.x;
    if (idx >= nd4) return;
    float4* o = (float4*)out;
    float4 u0 = o[idx];
    float4 u1 = o[nd4 + idx];
    float4 u2 = o[2 * nd4 + idx];
    const float s1 = 0.7310585786300049f;
    float4 e1, e2;
    e1.x = 0.25f * u0.x + 0.5f * u1.x;
    e1.y = 0.25f * u0.y + 0.5f * u1.y;
    e1.z = 0.25f * u0.z + 0.5f * u1.z;
    e1.w = 0.25f * u0.w + 0.5f * u1.w;
    e2.x = (0.5f * u0.x + s1 * e1.x) * 0.25f + 0.5f * u2.x;
    e2.y = (0.5f * u0.y + s1 * e1.y) * 0.25f + 0.5f * u2.y;
    e2.z = (0.5f * u0.z + s1 * e1.z) * 0.25f + 0.5f * u2.z;
    e2.w = (0.5f * u0.w + s1 * e1.w) * 0.25f + 0.5f * u2.w;
    o[nd4 + idx] = e1;
    o[2 * nd4 + idx] = e2;
}

extern "C" void kernel_launch(void* const* d_in, const int* in_sizes, int n_in,
                              void* d_out, int out_size, void* d_ws, size_t ws_size,
                              hipStream_t stream) {
    const float* x_all = (const float*)d_in[0];
    const int*   nbrs  = (const int*)d_in[1];
    float*       out   = (float*)d_out;

    const int total_threads = T * N * 64;  // one wave per (t,node)
    eaconv_agg<<<(total_threads + 255) / 256, 256, 0, stream>>>(x_all, nbrs, out);
    eaconv_combine<<<(N * D / 4 + 255) / 256, 256, 0, stream>>>(out);
}